// Round 1
// 347.129 us; speedup vs baseline: 1.0031x; 1.0031x over previous
//
#include <hip/hip_runtime.h>

// 4 lanes cooperate on one row (16 floats = 64 B = exactly one cache line).
// Lane q = tid&3 loads float4 #q of the row -> every wave-level pts load is
// lane-contiguous (16 distinct 64B lines / instruction, memcpy-grade pattern),
// vs the old 1-row-per-thread layout (64 lines / instruction, 4x TA work).
// Rows with nt = num_of_inter-2 <= 0 (1/3 of rows) contribute 0 and their
// 64B line is never fetched (quad-uniform exec mask skip).
__global__ __launch_bounds__(256) void rinter_area_kernel(
    const float4* __restrict__ pts4,
    const int* __restrict__ num_of_inter,
    float* __restrict__ out,
    int n)
{
    const int q = threadIdx.x & 3;               // quarter of the row this lane owns
    const int gpb = blockDim.x >> 2;             // rows per block = 64
    const int gstride = gridDim.x * gpb;         // rows per grid-stride step
    int row = blockIdx.x * gpb + (threadIdx.x >> 2);

    // Prefetch num one iteration ahead: removes the num->pts dependent-load
    // chain (two serialized ~900cy HBM latencies) from the steady-state path.
    int nv = (row < n) ? num_of_inter[row] : 2;  // OOB -> nt = 0

    while (row < n) {
        int nrow = row + gstride;
        int nnv = (nrow < n) ? num_of_inter[nrow] : 2;

        int nt = nv - 2;                         // triangles to sum, in [-2, 6]
        float acc = 0.0f;
        if (nt > 0) {                            // quad-uniform predicate
            // lane q holds points 2q (a.x,a.y) and 2q+1 (a.z,a.w)
            float4 a = pts4[(size_t)row * 4 + q];

            // broadcast p1 = point 0 (lives in lane q==0 of the quad)
            float p1x = __shfl(a.x, 0, 4);
            float p1y = __shfl(a.y, 0, 4);
            // next quad-lane's low point = point 2q+2
            float nx2 = __shfl_down(a.x, 1, 4);
            float ny2 = __shfl_down(a.y, 1, 4);

            // triangle A: (p1, pt2q, pt2q+1) == global j = 2q-1
            //   (for q==0 this degenerates to area 0: p2 == p1)
            float crossA = (p1x - a.z) * (a.y - a.w) - (p1y - a.w) * (a.x - a.z);
            // triangle B: (p1, pt2q+1, pt2q+2) == global j = 2q
            //   (for q==3, j=6 never active; nx2/ny2 garbage is masked out)
            float crossB = (p1x - nx2) * (a.w - ny2) - (p1y - ny2) * (a.z - nx2);

            acc  = (nt > 2 * q - 1) ? fabsf(crossA) * 0.5f : 0.0f;
            acc += (nt > 2 * q)     ? fabsf(crossB) * 0.5f : 0.0f;

            // quad butterfly reduction (all 4 lanes active together)
            acc += __shfl_xor(acc, 1, 4);
            acc += __shfl_xor(acc, 2, 4);
        }
        // lanes q==0 of a wave write 16 consecutive dwords = one 64B segment
        if (q == 0) out[row] = acc;

        row = nrow;
        nv = nnv;
    }
}

extern "C" void kernel_launch(void* const* d_in, const int* in_sizes, int n_in,
                              void* d_out, int out_size, void* d_ws, size_t ws_size,
                              hipStream_t stream) {
    const float4* pts4          = (const float4*)d_in[0];
    const int*    num_of_inter  = (const int*)d_in[1];
    float*        out           = (float*)d_out;
    int n = in_sizes[1];  // one num_of_inter entry per row

    const int block = 256;                 // 64 rows per block
    int blocks_needed = (n + 63) / 64;
    int grid = blocks_needed < 2048 ? blocks_needed : 2048;  // 2048*256 thr = 8192 waves = full chip
    rinter_area_kernel<<<grid, block, 0, stream>>>(pts4, num_of_inter, out, n);
}